// Round 2
// baseline (202.537 us; speedup 1.0000x reference)
//
#include <hip/hip_runtime.h>

// NeRF positional encoding: x[rows,4] -> out[rows,768]
// Per row: 64-float block [sin/cos of 2^l*pi*x_c, l=0..7, c=0..3], tiled 12x.
// Write-BW bound: 201 MB out / 1 MB in.
//
// V2 changes vs V1 (one wave/row, 3 plain stores):
//  - G=8 rows per wave: 24 outstanding 16B stores/lane, 8x fewer waves.
//  - nontemporal stores: output is write-once; bypass L2/LLC allocation so we
//    don't force writebacks of the harness's dirty poison lines inside our
//    timed window (fill leaves 768 MiB dirty through a 256 MiB LLC right
//    before us).
//  - nt builtin needs a clang vector type, not HIP's float4 class.
// Lane i owns float4 chunk (i&15) of the 16-chunk block; that chunk is valid
// at positions j = it*64 + lane, it=0..2, within the row's 192 float4s.

typedef float f32x4 __attribute__((ext_vector_type(4)));

#define G 8  // rows per wave

__global__ __launch_bounds__(256) void nerf_pe_kernel(const float* __restrict__ x,
                                                      float* __restrict__ out,
                                                      int rows) {
    const int tid  = blockIdx.x * blockDim.x + threadIdx.x;
    const int wave = tid >> 6;
    const int lane = tid & 63;
    const int row0 = wave * G;
    if (row0 >= rows) return;

    const int   l    = (lane & 15) >> 1;     // freq index 0..7
    const int   half = lane & 1;             // 0 -> coords {0,1}, 1 -> coords {2,3}
    const float f    = 3.14159265358979f * (float)(1 << l);   // 2^l * pi

    // Batch the x loads: one float2 per row (the two coords this lane needs).
    // A wave touches G*16 B of x, L1/L2-friendly.
    const float2* x2 = reinterpret_cast<const float2*>(x);
    float2 xv[G];
#pragma unroll
    for (int i = 0; i < G; ++i) {
        const int r = row0 + i;
        xv[i] = x2[(size_t)min(r, rows - 1) * 2 + half];
    }

    f32x4 v[G];
#pragma unroll
    for (int i = 0; i < G; ++i) {
        const float a0 = f * xv[i].x;
        const float a1 = f * xv[i].y;
        v[i].x = __sinf(a0);   // v_sin_f32; max |a|/2pi = 64 rev, in HW range
        v[i].y = __cosf(a0);
        v[i].z = __sinf(a1);
        v[i].w = __cosf(a1);
    }

    // Stores: row i = 192 float4s at base + i*192; this lane writes chunks
    // {lane, lane+64, lane+128}. All addresses are base + compile-time offsets.
    f32x4* o = reinterpret_cast<f32x4*>(out + (size_t)row0 * 768) + lane;
#pragma unroll
    for (int i = 0; i < G; ++i) {
        if (row0 + i < rows) {
#pragma unroll
            for (int j = 0; j < 3; ++j) {
                __builtin_nontemporal_store(v[i], o + i * 192 + j * 64);
            }
        }
    }
}

extern "C" void kernel_launch(void* const* d_in, const int* in_sizes, int n_in,
                              void* d_out, int out_size, void* d_ws, size_t ws_size,
                              hipStream_t stream) {
    const float* x   = (const float*)d_in[0];
    float*       out = (float*)d_out;
    const int rows    = in_sizes[0] / 4;                 // 65536
    const int waves   = (rows + G - 1) / G;              // 8192
    const int threads = waves * 64;
    const int blocks  = (threads + 255) / 256;           // 2048
    nerf_pe_kernel<<<blocks, 256, 0, stream>>>(x, out, rows);
}

// Round 3
// 192.031 us; speedup vs baseline: 1.0547x; 1.0547x over previous
//
#include <hip/hip_runtime.h>

// NeRF positional encoding: x[rows,4] -> out[rows,768]
// Per row: 64-float block [sin/cos of 2^l*pi*x_c, l=0..7, c=0..3], tiled 12x.
//
// FINAL (reverted to best-verified V1). Why this is the ceiling here:
//  - Kernel writes 201 MB; pure-write roofline would be ~31 us.
//  - But the harness's timed iteration = 768 MiB poison fill + this kernel.
//    HBM must absorb ~960 MiB of writes per iteration; the fill's LLC drain
//    (~256 MiB leftover) overlaps our dispatch window.
//    Window accounting: ours = (256 MiB drain + 192 MiB out)/72us = 6.2 TB/s,
//    fill = ~704 MiB/120us = 5.9 TB/s -- both at the ~6.4-6.7 TB/s measured
//    write ceiling. The kernel's window is HBM-write-drain bound.
//  - Falsified levers: 8-rows/wave deep-MLP stores (no change) and
//    __builtin_nontemporal_store cache bypass (no change) -- downstream-bound.
//
// One wave per row; lane i owns float4 chunk (i&15) of the 64-float block,
// computes 2 sincos once, stores it 3x (chunks lane, lane+64, lane+128).
__global__ __launch_bounds__(256) void nerf_pe_kernel(const float* __restrict__ x,
                                                      float* __restrict__ out,
                                                      int rows) {
    const int tid  = blockIdx.x * blockDim.x + threadIdx.x;
    const int row  = tid >> 6;      // one 64-lane wave per row
    const int lane = tid & 63;
    if (row >= rows) return;

    // chunk k = lane & 15 within the 64-float block:
    //   freq index l = k >> 1, coord base c = 2*(k & 1)
    const int   l = (lane & 15) >> 1;
    const int   c = (lane & 1) << 1;
    const float f = 3.14159265358979f * (float)(1 << l);   // 2^l * pi (exact pow2 scale)

    const float x0 = x[row * 4 + c];
    const float x1 = x[row * 4 + c + 1];
    const float a0 = f * x0;
    const float a1 = f * x1;

    float4 v;
    v.x = __sinf(a0);   // v_sin_f32; max |a|/2pi = 64 rev, in HW range
    v.y = __cosf(a0);
    v.z = __sinf(a1);
    v.w = __cosf(a1);

    // row = 192 float4 chunks; this lane's value is valid at chunk
    // j = it*64 + lane for it = 0..2 (since j % 16 == lane % 16).
    float4* o = reinterpret_cast<float4*>(out + (size_t)row * 768) + lane;
    o[0]   = v;
    o[64]  = v;
    o[128] = v;
}

extern "C" void kernel_launch(void* const* d_in, const int* in_sizes, int n_in,
                              void* d_out, int out_size, void* d_ws, size_t ws_size,
                              hipStream_t stream) {
    const float* x   = (const float*)d_in[0];
    float*       out = (float*)d_out;
    const int rows    = in_sizes[0] / 4;          // 65536
    const int threads = rows * 64;                // one wave per row
    const int blocks  = (threads + 255) / 256;
    nerf_pe_kernel<<<blocks, 256, 0, stream>>>(x, out, rows);
}